// Round 13
// baseline (125.780 us; speedup 1.0000x reference)
//
#include <hip/hip_runtime.h>

#define BB    4
#define TE    1024
#define TD    512
#define HH    128
#define DTILE 4
#define ESTR  (TE + 8)              // e_s row stride: breaks d-bank aliasing
#define LOG2E 1.4426950408889634f

// Accurate-enough tanh for the proj epilogue (786K elems, off the hot path).
__device__ __forceinline__ float tanh_eval(float x) {
    float e = __builtin_amdgcn_exp2f(2.0f * LOG2E * x);
    return 1.0f - 2.0f * __builtin_amdgcn_rcpf(e + 1.0f);
}

// Combined fraction over 4 elements with v pre-folded into Bp = v*B:
// sum_i v_i*(A_i+B_i)/(1+A_i*B_i) = n/den. 17 full-rate ops, no trans.
__device__ __forceinline__ void quad_nd(float4 A, float4 B, float4 Bp, float4 v,
                                        float& n, float& den) {
    float n0 = fmaf(v.x, A.x, Bp.x), d0 = fmaf(A.x, B.x, 1.0f);
    float n1 = fmaf(v.y, A.y, Bp.y), d1 = fmaf(A.y, B.y, 1.0f);
    float n2 = fmaf(v.z, A.z, Bp.z), d2 = fmaf(A.z, B.z, 1.0f);
    float n3 = fmaf(v.w, A.w, Bp.w), d3 = fmaf(A.w, B.w, 1.0f);
    float n01 = fmaf(n0, d1, n1 * d0), d01 = d0 * d1;
    float n23 = fmaf(n2, d3, n3 * d2), d23 = d2 * d3;
    n   = fmaf(n01, d23, n23 * d01);
    den = d01 * d23;
}

// ---------------------------------------------------------------------------
// Kernel 1: tiled projections; epilogue applies tanh (A = tanh(enc@W),
// B = tanh(dec@U)) so the energy kernel can use the addition theorem.
// ---------------------------------------------------------------------------
__global__ __launch_bounds__(256) void proj_gemm(
    const float* __restrict__ enc, const float* __restrict__ dec,
    const float* __restrict__ Wa,  const float* __restrict__ Ua,
    float* __restrict__ out)
{
    __shared__ float Xs[64 * 33];
    __shared__ float Ws[32 * 64];

    const int tid = threadIdx.x;
    const int rt = blockIdx.x >> 1, ch = blockIdx.x & 1;
    const int r0 = rt * 64, c0 = ch * 64;

    const float* X; const float* W; int rX0;
    if (r0 < BB * TE) { X = enc; W = Wa; rX0 = r0; }
    else              { X = dec; W = Ua; rX0 = r0 - BB * TE; }

    const int c4 = tid & 15;
    const int rg = tid >> 4;

    float4 a0 = {0,0,0,0}, a1 = a0, a2 = a0, a3 = a0;

    for (int kc = 0; kc < 4; ++kc) {
        #pragma unroll
        for (int i = 0; i < 2; ++i) {
            int idx = tid + i * 256;
            int r  = idx >> 3, k4 = idx & 7;
            *(float4*)&Xs[r * 33 + k4 * 4] =
                *(const float4*)&X[(rX0 + r) * HH + kc * 32 + k4 * 4];
            int kk = idx >> 4, cc = idx & 15;
            *(float4*)&Ws[kk * 64 + cc * 4] =
                *(const float4*)&W[(kc * 32 + kk) * HH + c0 + cc * 4];
        }
        __syncthreads();
        #pragma unroll 8
        for (int k = 0; k < 32; ++k) {
            float4 wv = *(const float4*)&Ws[k * 64 + c4 * 4];
            float x0 = Xs[(rg * 4 + 0) * 33 + k];
            float x1 = Xs[(rg * 4 + 1) * 33 + k];
            float x2 = Xs[(rg * 4 + 2) * 33 + k];
            float x3 = Xs[(rg * 4 + 3) * 33 + k];
            a0.x = fmaf(x0, wv.x, a0.x); a0.y = fmaf(x0, wv.y, a0.y);
            a0.z = fmaf(x0, wv.z, a0.z); a0.w = fmaf(x0, wv.w, a0.w);
            a1.x = fmaf(x1, wv.x, a1.x); a1.y = fmaf(x1, wv.y, a1.y);
            a1.z = fmaf(x1, wv.z, a1.z); a1.w = fmaf(x1, wv.w, a1.w);
            a2.x = fmaf(x2, wv.x, a2.x); a2.y = fmaf(x2, wv.y, a2.y);
            a2.z = fmaf(x2, wv.z, a2.z); a2.w = fmaf(x2, wv.w, a2.w);
            a3.x = fmaf(x3, wv.x, a3.x); a3.y = fmaf(x3, wv.y, a3.y);
            a3.z = fmaf(x3, wv.z, a3.z); a3.w = fmaf(x3, wv.w, a3.w);
        }
        __syncthreads();
    }

    float4 accs[4] = {a0, a1, a2, a3};
    #pragma unroll
    for (int j = 0; j < 4; ++j) {
        float4 o = accs[j];
        o.x = tanh_eval(o.x); o.y = tanh_eval(o.y);
        o.z = tanh_eval(o.z); o.w = tanh_eval(o.w);
        *(float4*)&out[(r0 + rg * 4 + j) * HH + c0 + c4 * 4] = o;
    }
}

// ---------------------------------------------------------------------------
// Kernel 2: fused energies -> softmax -> context. 1024 threads (16 waves),
// grid 512 -> 2 blocks/CU x 16 waves = 32 waves/CU (hw max, 8/SIMD) for
// latency hiding. Phase-1 lane groups of 8 compute 2 rows x 4 d per iter
// (R12 mapping); e_s stride TE+8 kills the d-bank conflict.
// ---------------------------------------------------------------------------
__global__ __launch_bounds__(1024, 2) void attn_fused(
    const float* __restrict__ enc,    // [B, TE, H] raw
    const float* __restrict__ ta,     // [B*TE, H]  = tanh(W_s)
    const float* __restrict__ tb,     // [B*TD, H]  = tanh(U_h)
    const float* __restrict__ Va,     // [H]
    float* __restrict__ c_out,        // [B, TD, H]
    float* __restrict__ e_out)        // [B, TD, TE]
{
    __shared__ float e_s[DTILE * ESTR];       // 16.1 KB
    __shared__ float c_red[16 * DTILE * HH];  // 32 KB

    const int tid = threadIdx.x;
    const int l   = tid & 63;
    const int w   = tid >> 6;            // 0..15
    const int b   = blockIdx.x >> 7;
    const int d0  = (blockIdx.x & 127) * DTILE;

    // ---------------- Phase 1: energies ----------------
    {
        const int g  = l >> 3;           // group 0..7
        const int hl = l & 7;            // h-chunk offset within group
        const int dl = g & 3;            // this group's decoder step
        const int rh = g >> 2;           // row parity

        float4 Bv[4], Bp[4], v4[4];
        #pragma unroll
        for (int j = 0; j < 4; ++j) {
            v4[j] = *(const float4*)&Va[(j * 8 + hl) * 4];
            float4 bb = *(const float4*)&tb[((size_t)b * TD + d0 + dl) * HH + (j * 8 + hl) * 4];
            Bv[j] = bb;
            Bp[j] = make_float4(v4[j].x * bb.x, v4[j].y * bb.y,
                                v4[j].z * bb.z, v4[j].w * bb.w);
        }

        const float* ta_b = ta + (size_t)b * TE * HH;

        // Wave w owns rows w*4 + {0..3} of each 64-row stripe; 32 iters.
        auto rowOf = [&](int i) {
            return ((i >> 1) << 6) + w * 4 + ((i & 1) << 1) + rh;
        };

        float4 A0[4], A1[4];
        auto loadA = [&](int i, float4 (&A)[4]) {
            const float* base = ta_b + (size_t)rowOf(i) * HH;
            #pragma unroll
            for (int j = 0; j < 4; ++j)
                A[j] = *(const float4*)&base[(j * 8 + hl) * 4];
        };

        auto p1c = [&](int i, float4 (&A)[4]) {
            float n[4], dd[4];
            #pragma unroll
            for (int j = 0; j < 4; ++j)
                quad_nd(A[j], Bv[j], Bp[j], v4[j], n[j], dd[j]);
            float n01 = fmaf(n[0], dd[1], n[1] * dd[0]), d01 = dd[0] * dd[1];
            float n23 = fmaf(n[2], dd[3], n[3] * dd[2]), d23 = dd[2] * dd[3];
            float num = fmaf(n01, d23, n23 * d01);
            float den = d01 * d23;
            float e = num * __builtin_amdgcn_rcpf(den);
            e += __shfl_xor(e, 1);
            e += __shfl_xor(e, 2);
            e += __shfl_xor(e, 4);
            if (hl == 0) e_s[dl * ESTR + rowOf(i)] = e;
        };

        loadA(0, A0);
        #pragma unroll 1
        for (int i = 0; i < 30; i += 2) {
            loadA(i + 1, A1);
            p1c(i, A0);
            loadA(i + 2, A0);
            p1c(i + 1, A1);
        }
        loadA(31, A1);
        p1c(30, A0);
        p1c(31, A1);
    }
    __syncthreads();   // all waves' raw energies visible

    // ---------------- Phase 2: softmax (d = w&3, 4 waves split quarters) ----
    {
        const int d2 = w & 3, hf = w >> 2;   // hf in 0..3
        float ev[16];
        float m = -3.0e38f;
        #pragma unroll
        for (int i = 0; i < 16; ++i) {
            ev[i] = e_s[d2 * ESTR + i * 64 + l];
            m = fmaxf(m, ev[i]);
        }
        #pragma unroll
        for (int off = 32; off; off >>= 1) m = fmaxf(m, __shfl_xor(m, off));
        float s = 0.f;
        #pragma unroll
        for (int i = 0; i < 16; ++i) {
            ev[i] = __builtin_amdgcn_exp2f((ev[i] - m) * LOG2E);
            s += ev[i];
        }
        #pragma unroll
        for (int off = 32; off; off >>= 1) s += __shfl_xor(s, off);
        float inv = __builtin_amdgcn_rcpf(s);

        __syncthreads();   // all raw-energy reads done before overwrite
        float* eo = e_out + ((size_t)b * TD + d0 + d2) * TE;
        #pragma unroll
        for (int i = 0; i < 4; ++i) {
            int ii = hf * 4 + i;
            float p = ev[ii] * inv;
            e_s[d2 * ESTR + ii * 64 + l] = p;
            eo[ii * 64 + l] = p;
        }
        __syncthreads();   // normalized p visible to all waves
    }

    // ---------------- Phase 3: context (register pingpong) ------------------
    const int h4 = l & 31, tsub = l >> 5;
    float4 acc4[DTILE];
    #pragma unroll
    for (int d = 0; d < DTILE; ++d) acc4[d] = make_float4(0.f, 0.f, 0.f, 0.f);

    {
        const float* enc_w = enc + ((size_t)b * TE + w * 4) * HH;
        float4 X0[2], X1[2];

        auto loadX = [&](int tt, float4 (&X)[2]) {
            const float* base = enc_w + (size_t)tt * 64 * HH;
            #pragma unroll
            for (int k = 0; k < 2; ++k)
                X[k] = *(const float4*)&base[(tsub * 2 + k) * HH + h4 * 4];
        };

        auto p3c = [&](int tt, float4 (&X)[2]) {
            float2 ep[DTILE];
            #pragma unroll
            for (int d = 0; d < DTILE; ++d)
                ep[d] = *(const float2*)&e_s[d * ESTR + tt * 64 + w * 4 + tsub * 2];
            #pragma unroll
            for (int k = 0; k < 2; ++k) {
                float4 x = X[k];
                float p0 = k == 0 ? ep[0].x : ep[0].y;
                float p1 = k == 0 ? ep[1].x : ep[1].y;
                float p2 = k == 0 ? ep[2].x : ep[2].y;
                float p3 = k == 0 ? ep[3].x : ep[3].y;
                acc4[0].x = fmaf(p0, x.x, acc4[0].x); acc4[0].y = fmaf(p0, x.y, acc4[0].y);
                acc4[0].z = fmaf(p0, x.z, acc4[0].z); acc4[0].w = fmaf(p0, x.w, acc4[0].w);
                acc4[1].x = fmaf(p1, x.x, acc4[1].x); acc4[1].y = fmaf(p1, x.y, acc4[1].y);
                acc4[1].z = fmaf(p1, x.z, acc4[1].z); acc4[1].w = fmaf(p1, x.w, acc4[1].w);
                acc4[2].x = fmaf(p2, x.x, acc4[2].x); acc4[2].y = fmaf(p2, x.y, acc4[2].y);
                acc4[2].z = fmaf(p2, x.z, acc4[2].z); acc4[2].w = fmaf(p2, x.w, acc4[2].w);
                acc4[3].x = fmaf(p3, x.x, acc4[3].x); acc4[3].y = fmaf(p3, x.y, acc4[3].y);
                acc4[3].z = fmaf(p3, x.z, acc4[3].z); acc4[3].w = fmaf(p3, x.w, acc4[3].w);
            }
        };

        loadX(0, X0);
        #pragma unroll 1
        for (int tt = 0; tt < 14; tt += 2) {
            loadX(tt + 1, X1);
            p3c(tt, X0);
            loadX(tt + 2, X0);
            p3c(tt + 1, X1);
        }
        loadX(15, X1);
        p3c(14, X0);
        p3c(15, X1);
    }

    // Combine tsub halves; park per-wave partials; tree-reduce across waves.
    #pragma unroll
    for (int d = 0; d < DTILE; ++d) {
        acc4[d].x += __shfl_xor(acc4[d].x, 32);
        acc4[d].y += __shfl_xor(acc4[d].y, 32);
        acc4[d].z += __shfl_xor(acc4[d].z, 32);
        acc4[d].w += __shfl_xor(acc4[d].w, 32);
    }
    if (tsub == 0) {
        #pragma unroll
        for (int d = 0; d < DTILE; ++d)
            *(float4*)&c_red[(w * DTILE + d) * HH + h4 * 4] = acc4[d];
    }
    __syncthreads();

    if (w < DTILE && l < 32) {
        float4 o = make_float4(0.f, 0.f, 0.f, 0.f);
        #pragma unroll
        for (int ww = 0; ww < 16; ++ww) {
            float4 p = *(const float4*)&c_red[(ww * DTILE + w) * HH + l * 4];
            o.x += p.x; o.y += p.y; o.z += p.z; o.w += p.w;
        }
        *(float4*)&c_out[((size_t)b * TD + d0 + w) * HH + l * 4] = o;
    }
}

// ---------------------------------------------------------------------------
extern "C" void kernel_launch(void* const* d_in, const int* in_sizes, int n_in,
                              void* d_out, int out_size, void* d_ws, size_t ws_size,
                              hipStream_t stream) {
    (void)in_sizes; (void)n_in; (void)out_size; (void)ws_size;

    const float* enc = (const float*)d_in[0];
    const float* dec = (const float*)d_in[1];
    const float* Wa  = (const float*)d_in[2];
    const float* Ua  = (const float*)d_in[3];
    const float* Va  = (const float*)d_in[4];

    float* c_out = (float*)d_out;
    float* e_out = (float*)d_out + BB * TD * HH;

    float* proj = (float*)d_ws;
    float* ta_p = proj;                  // tanh(W_s): [B*TE, H]
    float* tb_p = proj + BB * TE * HH;   // tanh(U_h): [B*TD, H]

    proj_gemm<<<192, 256, 0, stream>>>(enc, dec, Wa, Ua, proj);
    attn_fused<<<(BB * TD) / DTILE, 1024, 0, stream>>>(enc, ta_p, tb_p, Va, c_out, e_out);
}

// Round 14
// 125.630 us; speedup vs baseline: 1.0012x; 1.0012x over previous
//
#include <hip/hip_runtime.h>

#define BB    4
#define TE    1024
#define TD    512
#define HH    128
#define DTILE 4
#define TTILE 64
#define ESTR  (TE + 8)              // e_s row stride: breaks d-bank aliasing
#define LOG2E 1.4426950408889634f

// Accurate-enough tanh for the proj epilogue (786K elems, off the hot path).
__device__ __forceinline__ float tanh_eval(float x) {
    float e = __builtin_amdgcn_exp2f(2.0f * LOG2E * x);
    return 1.0f - 2.0f * __builtin_amdgcn_rcpf(e + 1.0f);
}

// Combined fraction over 4 elements with v pre-folded into Bp = v*B:
// sum_i v_i*(A_i+B_i)/(1+A_i*B_i) = n/den. 17 full-rate ops, no trans.
__device__ __forceinline__ void quad_nd(float4 A, float4 B, float4 Bp, float4 v,
                                        float& n, float& den) {
    float n0 = fmaf(v.x, A.x, Bp.x), d0 = fmaf(A.x, B.x, 1.0f);
    float n1 = fmaf(v.y, A.y, Bp.y), d1 = fmaf(A.y, B.y, 1.0f);
    float n2 = fmaf(v.z, A.z, Bp.z), d2 = fmaf(A.z, B.z, 1.0f);
    float n3 = fmaf(v.w, A.w, Bp.w), d3 = fmaf(A.w, B.w, 1.0f);
    float n01 = fmaf(n0, d1, n1 * d0), d01 = d0 * d1;
    float n23 = fmaf(n2, d3, n3 * d2), d23 = d2 * d3;
    n   = fmaf(n01, d23, n23 * d01);
    den = d01 * d23;
}

// ---------------------------------------------------------------------------
// Kernel 1: tiled projections; epilogue applies tanh (A = tanh(enc@W),
// B = tanh(dec@U)) so the energy kernel can use the addition theorem.
// ---------------------------------------------------------------------------
__global__ __launch_bounds__(256) void proj_gemm(
    const float* __restrict__ enc, const float* __restrict__ dec,
    const float* __restrict__ Wa,  const float* __restrict__ Ua,
    float* __restrict__ out)
{
    __shared__ float Xs[64 * 33];
    __shared__ float Ws[32 * 64];

    const int tid = threadIdx.x;
    const int rt = blockIdx.x >> 1, ch = blockIdx.x & 1;
    const int r0 = rt * 64, c0 = ch * 64;

    const float* X; const float* W; int rX0;
    if (r0 < BB * TE) { X = enc; W = Wa; rX0 = r0; }
    else              { X = dec; W = Ua; rX0 = r0 - BB * TE; }

    const int c4 = tid & 15;
    const int rg = tid >> 4;

    float4 a0 = {0,0,0,0}, a1 = a0, a2 = a0, a3 = a0;

    for (int kc = 0; kc < 4; ++kc) {
        #pragma unroll
        for (int i = 0; i < 2; ++i) {
            int idx = tid + i * 256;
            int r  = idx >> 3, k4 = idx & 7;
            *(float4*)&Xs[r * 33 + k4 * 4] =
                *(const float4*)&X[(rX0 + r) * HH + kc * 32 + k4 * 4];
            int kk = idx >> 4, cc = idx & 15;
            *(float4*)&Ws[kk * 64 + cc * 4] =
                *(const float4*)&W[(kc * 32 + kk) * HH + c0 + cc * 4];
        }
        __syncthreads();
        #pragma unroll 8
        for (int k = 0; k < 32; ++k) {
            float4 wv = *(const float4*)&Ws[k * 64 + c4 * 4];
            float x0 = Xs[(rg * 4 + 0) * 33 + k];
            float x1 = Xs[(rg * 4 + 1) * 33 + k];
            float x2 = Xs[(rg * 4 + 2) * 33 + k];
            float x3 = Xs[(rg * 4 + 3) * 33 + k];
            a0.x = fmaf(x0, wv.x, a0.x); a0.y = fmaf(x0, wv.y, a0.y);
            a0.z = fmaf(x0, wv.z, a0.z); a0.w = fmaf(x0, wv.w, a0.w);
            a1.x = fmaf(x1, wv.x, a1.x); a1.y = fmaf(x1, wv.y, a1.y);
            a1.z = fmaf(x1, wv.z, a1.z); a1.w = fmaf(x1, wv.w, a1.w);
            a2.x = fmaf(x2, wv.x, a2.x); a2.y = fmaf(x2, wv.y, a2.y);
            a2.z = fmaf(x2, wv.z, a2.z); a2.w = fmaf(x2, wv.w, a2.w);
            a3.x = fmaf(x3, wv.x, a3.x); a3.y = fmaf(x3, wv.y, a3.y);
            a3.z = fmaf(x3, wv.z, a3.z); a3.w = fmaf(x3, wv.w, a3.w);
        }
        __syncthreads();
    }

    float4 accs[4] = {a0, a1, a2, a3};
    #pragma unroll
    for (int j = 0; j < 4; ++j) {
        float4 o = accs[j];
        o.x = tanh_eval(o.x); o.y = tanh_eval(o.y);
        o.z = tanh_eval(o.z); o.w = tanh_eval(o.w);
        *(float4*)&out[(r0 + rg * 4 + j) * HH + c0 + c4 * 4] = o;
    }
}

// ---------------------------------------------------------------------------
// Kernel 2: fused energies -> softmax -> context. R12 structure (best) with
// (a) e_s stride TE+8 (conflict-free d-writes), (b) DEPTH-4 register
// pipeline in phase 1 (loads 3 iterations ahead cover L2 latency).
// ---------------------------------------------------------------------------
__global__ __launch_bounds__(512, 4) void attn_fused(
    const float* __restrict__ enc,    // [B, TE, H] raw
    const float* __restrict__ ta,     // [B*TE, H]  = tanh(W_s)
    const float* __restrict__ tb,     // [B*TD, H]  = tanh(U_h)
    const float* __restrict__ Va,     // [H]
    float* __restrict__ c_out,        // [B, TD, H]
    float* __restrict__ e_out)        // [B, TD, TE]
{
    __shared__ float e_s[DTILE * ESTR];     // 16.1 KB
    __shared__ float c_red[8 * DTILE * HH]; // 16 KB

    const int tid = threadIdx.x;
    const int l   = tid & 63;
    const int w   = tid >> 6;            // 0..7 (row-octet owner)
    const int b   = blockIdx.x >> 7;
    const int d0  = (blockIdx.x & 127) * DTILE;

    // ---------------- Phase 1: energies ----------------
    {
        const int g  = l >> 3;           // group 0..7
        const int hl = l & 7;            // h-chunk offset within group
        const int dl = g & 3;            // this group's decoder step
        const int rh = g >> 2;           // row parity

        float4 Bv[4], Bp[4], v4[4];
        #pragma unroll
        for (int j = 0; j < 4; ++j) {
            v4[j] = *(const float4*)&Va[(j * 8 + hl) * 4];
            float4 bb = *(const float4*)&tb[((size_t)b * TD + d0 + dl) * HH + (j * 8 + hl) * 4];
            Bv[j] = bb;
            Bp[j] = make_float4(v4[j].x * bb.x, v4[j].y * bb.y,
                                v4[j].z * bb.z, v4[j].w * bb.w);
        }

        const float* ta_b = ta + (size_t)b * TE * HH;

        // Wave w covers rows {(i>>2)*64 + w*8 + (i&3)*2 + rh}, i = 0..63.
        auto rowOf = [&](int i) {
            return ((i >> 2) << 6) + w * 8 + ((i & 3) << 1) + rh;
        };

        float4 Ab[4][4];   // 4-deep pipeline, 4 float4 per buffer
        auto loadA = [&](int i, float4 (&A)[4]) {
            const float* base = ta_b + (size_t)rowOf(i) * HH;
            #pragma unroll
            for (int j = 0; j < 4; ++j)
                A[j] = *(const float4*)&base[(j * 8 + hl) * 4];
        };

        auto p1c = [&](int i, float4 (&A)[4]) {
            float n[4], dd[4];
            #pragma unroll
            for (int j = 0; j < 4; ++j)
                quad_nd(A[j], Bv[j], Bp[j], v4[j], n[j], dd[j]);
            float n01 = fmaf(n[0], dd[1], n[1] * dd[0]), d01 = dd[0] * dd[1];
            float n23 = fmaf(n[2], dd[3], n[3] * dd[2]), d23 = dd[2] * dd[3];
            float num = fmaf(n01, d23, n23 * d01);
            float den = d01 * d23;
            float e = num * __builtin_amdgcn_rcpf(den);
            e += __shfl_xor(e, 1);
            e += __shfl_xor(e, 2);
            e += __shfl_xor(e, 4);
            if (hl == 0) e_s[dl * ESTR + rowOf(i)] = e;
        };

        loadA(0, Ab[0]);
        loadA(1, Ab[1]);
        loadA(2, Ab[2]);
        #pragma unroll 1
        for (int i = 0; i < 60; i += 4) {
            loadA(i + 3, Ab[3]); p1c(i + 0, Ab[0]);
            loadA(i + 4, Ab[0]); p1c(i + 1, Ab[1]);
            loadA(i + 5, Ab[1]); p1c(i + 2, Ab[2]);
            loadA(i + 6, Ab[2]); p1c(i + 3, Ab[3]);
        }
        loadA(63, Ab[3]);
        p1c(60, Ab[0]);
        p1c(61, Ab[1]);
        p1c(62, Ab[2]);
        p1c(63, Ab[3]);
    }
    __syncthreads();   // all waves' raw energies visible

    // ---------------- Phase 2: softmax (d = w&3, two waves split halves) ----
    {
        const int d2 = w & 3, hf = w >> 2;
        float ev[16];
        float m = -3.0e38f;
        #pragma unroll
        for (int i = 0; i < 16; ++i) {
            ev[i] = e_s[d2 * ESTR + i * 64 + l];
            m = fmaxf(m, ev[i]);
        }
        #pragma unroll
        for (int off = 32; off; off >>= 1) m = fmaxf(m, __shfl_xor(m, off));
        float s = 0.f;
        #pragma unroll
        for (int i = 0; i < 16; ++i) {
            ev[i] = __builtin_amdgcn_exp2f((ev[i] - m) * LOG2E);
            s += ev[i];
        }
        #pragma unroll
        for (int off = 32; off; off >>= 1) s += __shfl_xor(s, off);
        float inv = __builtin_amdgcn_rcpf(s);

        __syncthreads();   // all raw-energy reads done before overwrite
        float* eo = e_out + ((size_t)b * TD + d0 + d2) * TE;
        #pragma unroll
        for (int i = 0; i < 8; ++i) {
            int ii = hf * 8 + i;
            float p = ev[ii] * inv;
            e_s[d2 * ESTR + ii * 64 + l] = p;
            eo[ii * 64 + l] = p;
        }
        __syncthreads();   // normalized p visible to all waves
    }

    // ---------------- Phase 3: context (register pingpong) ------------------
    const int h4 = l & 31, tsub = l >> 5;
    float4 acc4[DTILE];
    #pragma unroll
    for (int d = 0; d < DTILE; ++d) acc4[d] = make_float4(0.f, 0.f, 0.f, 0.f);

    {
        const float* enc_w = enc + ((size_t)b * TE + w * 8) * HH;
        float4 X0[4], X1[4];

        auto loadX = [&](int tt, float4 (&X)[4]) {
            const float* base = enc_w + (size_t)tt * TTILE * HH;
            #pragma unroll
            for (int k = 0; k < 4; ++k)
                X[k] = *(const float4*)&base[(tsub * 4 + k) * HH + h4 * 4];
        };

        auto p3c = [&](int tt, float4 (&X)[4]) {
            float4 ep[DTILE];
            #pragma unroll
            for (int d = 0; d < DTILE; ++d)
                ep[d] = *(const float4*)&e_s[d * ESTR + tt * TTILE + w * 8 + tsub * 4];
            #pragma unroll
            for (int k = 0; k < 4; ++k) {
                float4 x = X[k];
                float p0 = k == 0 ? ep[0].x : k == 1 ? ep[0].y : k == 2 ? ep[0].z : ep[0].w;
                float p1 = k == 0 ? ep[1].x : k == 1 ? ep[1].y : k == 2 ? ep[1].z : ep[1].w;
                float p2 = k == 0 ? ep[2].x : k == 1 ? ep[2].y : k == 2 ? ep[2].z : ep[2].w;
                float p3 = k == 0 ? ep[3].x : k == 1 ? ep[3].y : k == 2 ? ep[3].z : ep[3].w;
                acc4[0].x = fmaf(p0, x.x, acc4[0].x); acc4[0].y = fmaf(p0, x.y, acc4[0].y);
                acc4[0].z = fmaf(p0, x.z, acc4[0].z); acc4[0].w = fmaf(p0, x.w, acc4[0].w);
                acc4[1].x = fmaf(p1, x.x, acc4[1].x); acc4[1].y = fmaf(p1, x.y, acc4[1].y);
                acc4[1].z = fmaf(p1, x.z, acc4[1].z); acc4[1].w = fmaf(p1, x.w, acc4[1].w);
                acc4[2].x = fmaf(p2, x.x, acc4[2].x); acc4[2].y = fmaf(p2, x.y, acc4[2].y);
                acc4[2].z = fmaf(p2, x.z, acc4[2].z); acc4[2].w = fmaf(p2, x.w, acc4[2].w);
                acc4[3].x = fmaf(p3, x.x, acc4[3].x); acc4[3].y = fmaf(p3, x.y, acc4[3].y);
                acc4[3].z = fmaf(p3, x.z, acc4[3].z); acc4[3].w = fmaf(p3, x.w, acc4[3].w);
            }
        };

        loadX(0, X0);
        #pragma unroll 1
        for (int tt = 0; tt < 14; tt += 2) {
            loadX(tt + 1, X1);
            p3c(tt, X0);
            loadX(tt + 2, X0);
            p3c(tt + 1, X1);
        }
        loadX(15, X1);
        p3c(14, X0);
        p3c(15, X1);
    }

    // Combine tsub halves; park per-wave partials; tree-reduce across waves.
    #pragma unroll
    for (int d = 0; d < DTILE; ++d) {
        acc4[d].x += __shfl_xor(acc4[d].x, 32);
        acc4[d].y += __shfl_xor(acc4[d].y, 32);
        acc4[d].z += __shfl_xor(acc4[d].z, 32);
        acc4[d].w += __shfl_xor(acc4[d].w, 32);
    }
    if (tsub == 0) {
        #pragma unroll
        for (int d = 0; d < DTILE; ++d)
            *(float4*)&c_red[(w * DTILE + d) * HH + h4 * 4] = acc4[d];
    }
    __syncthreads();

    if (w < DTILE && l < 32) {
        float4 o = make_float4(0.f, 0.f, 0.f, 0.f);
        #pragma unroll
        for (int ww = 0; ww < 8; ++ww) {
            float4 p = *(const float4*)&c_red[(ww * DTILE + w) * HH + l * 4];
            o.x += p.x; o.y += p.y; o.z += p.z; o.w += p.w;
        }
        *(float4*)&c_out[((size_t)b * TD + d0 + w) * HH + l * 4] = o;
    }
}

// ---------------------------------------------------------------------------
extern "C" void kernel_launch(void* const* d_in, const int* in_sizes, int n_in,
                              void* d_out, int out_size, void* d_ws, size_t ws_size,
                              hipStream_t stream) {
    (void)in_sizes; (void)n_in; (void)out_size; (void)ws_size;

    const float* enc = (const float*)d_in[0];
    const float* dec = (const float*)d_in[1];
    const float* Wa  = (const float*)d_in[2];
    const float* Ua  = (const float*)d_in[3];
    const float* Va  = (const float*)d_in[4];

    float* c_out = (float*)d_out;
    float* e_out = (float*)d_out + BB * TD * HH;

    float* proj = (float*)d_ws;
    float* ta_p = proj;                  // tanh(W_s): [B*TE, H]
    float* tb_p = proj + BB * TE * HH;   // tanh(U_h): [B*TD, H]

    proj_gemm<<<192, 256, 0, stream>>>(enc, dec, Wa, Ua, proj);
    attn_fused<<<(BB * TD) / DTILE, 512, 0, stream>>>(enc, ta_p, tb_p, Va, c_out, e_out);
}

// Round 15
// 122.532 us; speedup vs baseline: 1.0265x; 1.0253x over previous
//
#include <hip/hip_runtime.h>

#define BB    4
#define TE    1024
#define TD    512
#define HH    128
#define DTILE 4
#define TTILE 64
#define ESTR  (TE + 8)              // e_s row stride: breaks d-bank aliasing
#define LOG2E 1.4426950408889634f

// Accurate-enough tanh for the proj epilogue (786K elems, off the hot path).
__device__ __forceinline__ float tanh_eval(float x) {
    float e = __builtin_amdgcn_exp2f(2.0f * LOG2E * x);
    return 1.0f - 2.0f * __builtin_amdgcn_rcpf(e + 1.0f);
}

// Combined fraction over 4 elements with v pre-folded into Bp = v*B:
// sum_i v_i*(A_i+B_i)/(1+A_i*B_i) = n/den. 17 full-rate ops, no trans.
__device__ __forceinline__ void quad_nd(float4 A, float4 B, float4 Bp, float4 v,
                                        float& n, float& den) {
    float n0 = fmaf(v.x, A.x, Bp.x), d0 = fmaf(A.x, B.x, 1.0f);
    float n1 = fmaf(v.y, A.y, Bp.y), d1 = fmaf(A.y, B.y, 1.0f);
    float n2 = fmaf(v.z, A.z, Bp.z), d2 = fmaf(A.z, B.z, 1.0f);
    float n3 = fmaf(v.w, A.w, Bp.w), d3 = fmaf(A.w, B.w, 1.0f);
    float n01 = fmaf(n0, d1, n1 * d0), d01 = d0 * d1;
    float n23 = fmaf(n2, d3, n3 * d2), d23 = d2 * d3;
    n   = fmaf(n01, d23, n23 * d01);
    den = d01 * d23;
}

// ---------------------------------------------------------------------------
// Kernel 1: tiled projections; epilogue applies tanh (A = tanh(enc@W),
// B = tanh(dec@U)) so the energy kernel can use the addition theorem.
// ---------------------------------------------------------------------------
__global__ __launch_bounds__(256) void proj_gemm(
    const float* __restrict__ enc, const float* __restrict__ dec,
    const float* __restrict__ Wa,  const float* __restrict__ Ua,
    float* __restrict__ out)
{
    __shared__ float Xs[64 * 33];
    __shared__ float Ws[32 * 64];

    const int tid = threadIdx.x;
    const int rt = blockIdx.x >> 1, ch = blockIdx.x & 1;
    const int r0 = rt * 64, c0 = ch * 64;

    const float* X; const float* W; int rX0;
    if (r0 < BB * TE) { X = enc; W = Wa; rX0 = r0; }
    else              { X = dec; W = Ua; rX0 = r0 - BB * TE; }

    const int c4 = tid & 15;
    const int rg = tid >> 4;

    float4 a0 = {0,0,0,0}, a1 = a0, a2 = a0, a3 = a0;

    for (int kc = 0; kc < 4; ++kc) {
        #pragma unroll
        for (int i = 0; i < 2; ++i) {
            int idx = tid + i * 256;
            int r  = idx >> 3, k4 = idx & 7;
            *(float4*)&Xs[r * 33 + k4 * 4] =
                *(const float4*)&X[(rX0 + r) * HH + kc * 32 + k4 * 4];
            int kk = idx >> 4, cc = idx & 15;
            *(float4*)&Ws[kk * 64 + cc * 4] =
                *(const float4*)&W[(kc * 32 + kk) * HH + c0 + cc * 4];
        }
        __syncthreads();
        #pragma unroll 8
        for (int k = 0; k < 32; ++k) {
            float4 wv = *(const float4*)&Ws[k * 64 + c4 * 4];
            float x0 = Xs[(rg * 4 + 0) * 33 + k];
            float x1 = Xs[(rg * 4 + 1) * 33 + k];
            float x2 = Xs[(rg * 4 + 2) * 33 + k];
            float x3 = Xs[(rg * 4 + 3) * 33 + k];
            a0.x = fmaf(x0, wv.x, a0.x); a0.y = fmaf(x0, wv.y, a0.y);
            a0.z = fmaf(x0, wv.z, a0.z); a0.w = fmaf(x0, wv.w, a0.w);
            a1.x = fmaf(x1, wv.x, a1.x); a1.y = fmaf(x1, wv.y, a1.y);
            a1.z = fmaf(x1, wv.z, a1.z); a1.w = fmaf(x1, wv.w, a1.w);
            a2.x = fmaf(x2, wv.x, a2.x); a2.y = fmaf(x2, wv.y, a2.y);
            a2.z = fmaf(x2, wv.z, a2.z); a2.w = fmaf(x2, wv.w, a2.w);
            a3.x = fmaf(x3, wv.x, a3.x); a3.y = fmaf(x3, wv.y, a3.y);
            a3.z = fmaf(x3, wv.z, a3.z); a3.w = fmaf(x3, wv.w, a3.w);
        }
        __syncthreads();
    }

    float4 accs[4] = {a0, a1, a2, a3};
    #pragma unroll
    for (int j = 0; j < 4; ++j) {
        float4 o = accs[j];
        o.x = tanh_eval(o.x); o.y = tanh_eval(o.y);
        o.z = tanh_eval(o.z); o.w = tanh_eval(o.w);
        *(float4*)&out[(r0 + rg * 4 + j) * HH + c0 + c4 * 4] = o;
    }
}

// ---------------------------------------------------------------------------
// Kernel 2: fused energies -> softmax -> context. R12 structure + ESTR
// padding + DEPTH-3 phase-1 register pipeline (distance-2 prefetch,
// 48 buffer VGPRs -- fits the 128-reg budget without spilling).
// ---------------------------------------------------------------------------
__global__ __launch_bounds__(512, 4) void attn_fused(
    const float* __restrict__ enc,    // [B, TE, H] raw
    const float* __restrict__ ta,     // [B*TE, H]  = tanh(W_s)
    const float* __restrict__ tb,     // [B*TD, H]  = tanh(U_h)
    const float* __restrict__ Va,     // [H]
    float* __restrict__ c_out,        // [B, TD, H]
    float* __restrict__ e_out)        // [B, TD, TE]
{
    __shared__ float e_s[DTILE * ESTR];     // 16.1 KB
    __shared__ float c_red[8 * DTILE * HH]; // 16 KB

    const int tid = threadIdx.x;
    const int l   = tid & 63;
    const int w   = tid >> 6;            // 0..7 (row-octet owner)
    const int b   = blockIdx.x >> 7;
    const int d0  = (blockIdx.x & 127) * DTILE;

    // ---------------- Phase 1: energies ----------------
    {
        const int g  = l >> 3;           // group 0..7
        const int hl = l & 7;            // h-chunk offset within group
        const int dl = g & 3;            // this group's decoder step
        const int rh = g >> 2;           // row parity

        float4 Bv[4], Bp[4], v4[4];
        #pragma unroll
        for (int j = 0; j < 4; ++j) {
            v4[j] = *(const float4*)&Va[(j * 8 + hl) * 4];
            float4 bb = *(const float4*)&tb[((size_t)b * TD + d0 + dl) * HH + (j * 8 + hl) * 4];
            Bv[j] = bb;
            Bp[j] = make_float4(v4[j].x * bb.x, v4[j].y * bb.y,
                                v4[j].z * bb.z, v4[j].w * bb.w);
        }

        const float* ta_b = ta + (size_t)b * TE * HH;

        // Wave w covers rows {(i>>2)*64 + w*8 + (i&3)*2 + rh}, i = 0..63.
        auto rowOf = [&](int i) {
            return ((i >> 2) << 6) + w * 8 + ((i & 3) << 1) + rh;
        };

        float4 Ab[3][4];   // 3-deep pipeline (distance-2 prefetch)
        auto loadA = [&](int i, float4 (&A)[4]) {
            const float* base = ta_b + (size_t)rowOf(i) * HH;
            #pragma unroll
            for (int j = 0; j < 4; ++j)
                A[j] = *(const float4*)&base[(j * 8 + hl) * 4];
        };

        auto p1c = [&](int i, float4 (&A)[4]) {
            float n[4], dd[4];
            #pragma unroll
            for (int j = 0; j < 4; ++j)
                quad_nd(A[j], Bv[j], Bp[j], v4[j], n[j], dd[j]);
            float n01 = fmaf(n[0], dd[1], n[1] * dd[0]), d01 = dd[0] * dd[1];
            float n23 = fmaf(n[2], dd[3], n[3] * dd[2]), d23 = dd[2] * dd[3];
            float num = fmaf(n01, d23, n23 * d01);
            float den = d01 * d23;
            float e = num * __builtin_amdgcn_rcpf(den);
            e += __shfl_xor(e, 1);
            e += __shfl_xor(e, 2);
            e += __shfl_xor(e, 4);
            if (hl == 0) e_s[dl * ESTR + rowOf(i)] = e;
        };

        loadA(0, Ab[0]);
        loadA(1, Ab[1]);
        #pragma unroll 1
        for (int i = 0; i < 60; i += 3) {
            loadA(i + 2, Ab[2]); p1c(i + 0, Ab[0]);
            loadA(i + 3, Ab[0]); p1c(i + 1, Ab[1]);
            loadA(i + 4, Ab[1]); p1c(i + 2, Ab[2]);
        }
        // i = 60..63 epilogue: Ab[0] has 60's data? (loop ended at i=57 pass:
        // loads issued for 59,60,61 -> Ab[2],Ab[0],Ab[1]; computed 57,58,59)
        loadA(62, Ab[2]);
        p1c(60, Ab[0]);
        loadA(63, Ab[0]);
        p1c(61, Ab[1]);
        p1c(62, Ab[2]);
        p1c(63, Ab[0]);
    }
    __syncthreads();   // all waves' raw energies visible

    // ---------------- Phase 2: softmax (d = w&3, two waves split halves) ----
    {
        const int d2 = w & 3, hf = w >> 2;
        float ev[16];
        float m = -3.0e38f;
        #pragma unroll
        for (int i = 0; i < 16; ++i) {
            ev[i] = e_s[d2 * ESTR + i * 64 + l];
            m = fmaxf(m, ev[i]);
        }
        #pragma unroll
        for (int off = 32; off; off >>= 1) m = fmaxf(m, __shfl_xor(m, off));
        float s = 0.f;
        #pragma unroll
        for (int i = 0; i < 16; ++i) {
            ev[i] = __builtin_amdgcn_exp2f((ev[i] - m) * LOG2E);
            s += ev[i];
        }
        #pragma unroll
        for (int off = 32; off; off >>= 1) s += __shfl_xor(s, off);
        float inv = __builtin_amdgcn_rcpf(s);

        __syncthreads();   // all raw-energy reads done before overwrite
        float* eo = e_out + ((size_t)b * TD + d0 + d2) * TE;
        #pragma unroll
        for (int i = 0; i < 8; ++i) {
            int ii = hf * 8 + i;
            float p = ev[ii] * inv;
            e_s[d2 * ESTR + ii * 64 + l] = p;
            eo[ii * 64 + l] = p;
        }
        __syncthreads();   // normalized p visible to all waves
    }

    // ---------------- Phase 3: context (register pingpong) ------------------
    const int h4 = l & 31, tsub = l >> 5;
    float4 acc4[DTILE];
    #pragma unroll
    for (int d = 0; d < DTILE; ++d) acc4[d] = make_float4(0.f, 0.f, 0.f, 0.f);

    {
        const float* enc_w = enc + ((size_t)b * TE + w * 8) * HH;
        float4 X0[4], X1[4];

        auto loadX = [&](int tt, float4 (&X)[4]) {
            const float* base = enc_w + (size_t)tt * TTILE * HH;
            #pragma unroll
            for (int k = 0; k < 4; ++k)
                X[k] = *(const float4*)&base[(tsub * 4 + k) * HH + h4 * 4];
        };

        auto p3c = [&](int tt, float4 (&X)[4]) {
            float4 ep[DTILE];
            #pragma unroll
            for (int d = 0; d < DTILE; ++d)
                ep[d] = *(const float4*)&e_s[d * ESTR + tt * TTILE + w * 8 + tsub * 4];
            #pragma unroll
            for (int k = 0; k < 4; ++k) {
                float4 x = X[k];
                float p0 = k == 0 ? ep[0].x : k == 1 ? ep[0].y : k == 2 ? ep[0].z : ep[0].w;
                float p1 = k == 0 ? ep[1].x : k == 1 ? ep[1].y : k == 2 ? ep[1].z : ep[1].w;
                float p2 = k == 0 ? ep[2].x : k == 1 ? ep[2].y : k == 2 ? ep[2].z : ep[2].w;
                float p3 = k == 0 ? ep[3].x : k == 1 ? ep[3].y : k == 2 ? ep[3].z : ep[3].w;
                acc4[0].x = fmaf(p0, x.x, acc4[0].x); acc4[0].y = fmaf(p0, x.y, acc4[0].y);
                acc4[0].z = fmaf(p0, x.z, acc4[0].z); acc4[0].w = fmaf(p0, x.w, acc4[0].w);
                acc4[1].x = fmaf(p1, x.x, acc4[1].x); acc4[1].y = fmaf(p1, x.y, acc4[1].y);
                acc4[1].z = fmaf(p1, x.z, acc4[1].z); acc4[1].w = fmaf(p1, x.w, acc4[1].w);
                acc4[2].x = fmaf(p2, x.x, acc4[2].x); acc4[2].y = fmaf(p2, x.y, acc4[2].y);
                acc4[2].z = fmaf(p2, x.z, acc4[2].z); acc4[2].w = fmaf(p2, x.w, acc4[2].w);
                acc4[3].x = fmaf(p3, x.x, acc4[3].x); acc4[3].y = fmaf(p3, x.y, acc4[3].y);
                acc4[3].z = fmaf(p3, x.z, acc4[3].z); acc4[3].w = fmaf(p3, x.w, acc4[3].w);
            }
        };

        loadX(0, X0);
        #pragma unroll 1
        for (int tt = 0; tt < 14; tt += 2) {
            loadX(tt + 1, X1);
            p3c(tt, X0);
            loadX(tt + 2, X0);
            p3c(tt + 1, X1);
        }
        loadX(15, X1);
        p3c(14, X0);
        p3c(15, X1);
    }

    // Combine tsub halves; park per-wave partials; tree-reduce across waves.
    #pragma unroll
    for (int d = 0; d < DTILE; ++d) {
        acc4[d].x += __shfl_xor(acc4[d].x, 32);
        acc4[d].y += __shfl_xor(acc4[d].y, 32);
        acc4[d].z += __shfl_xor(acc4[d].z, 32);
        acc4[d].w += __shfl_xor(acc4[d].w, 32);
    }
    if (tsub == 0) {
        #pragma unroll
        for (int d = 0; d < DTILE; ++d)
            *(float4*)&c_red[(w * DTILE + d) * HH + h4 * 4] = acc4[d];
    }
    __syncthreads();

    if (w < DTILE && l < 32) {
        float4 o = make_float4(0.f, 0.f, 0.f, 0.f);
        #pragma unroll
        for (int ww = 0; ww < 8; ++ww) {
            float4 p = *(const float4*)&c_red[(ww * DTILE + w) * HH + l * 4];
            o.x += p.x; o.y += p.y; o.z += p.z; o.w += p.w;
        }
        *(float4*)&c_out[((size_t)b * TD + d0 + w) * HH + l * 4] = o;
    }
}

// ---------------------------------------------------------------------------
extern "C" void kernel_launch(void* const* d_in, const int* in_sizes, int n_in,
                              void* d_out, int out_size, void* d_ws, size_t ws_size,
                              hipStream_t stream) {
    (void)in_sizes; (void)n_in; (void)out_size; (void)ws_size;

    const float* enc = (const float*)d_in[0];
    const float* dec = (const float*)d_in[1];
    const float* Wa  = (const float*)d_in[2];
    const float* Ua  = (const float*)d_in[3];
    const float* Va  = (const float*)d_in[4];

    float* c_out = (float*)d_out;
    float* e_out = (float*)d_out + BB * TD * HH;

    float* proj = (float*)d_ws;
    float* ta_p = proj;                  // tanh(W_s): [B*TE, H]
    float* tb_p = proj + BB * TE * HH;   // tanh(U_h): [B*TD, H]

    proj_gemm<<<192, 256, 0, stream>>>(enc, dec, Wa, Ua, proj);
    attn_fused<<<(BB * TD) / DTILE, 512, 0, stream>>>(enc, ta_p, tb_p, Va, c_out, e_out);
}

// Round 16
// 121.829 us; speedup vs baseline: 1.0324x; 1.0058x over previous
//
#include <hip/hip_runtime.h>

#define BB    4
#define TE    1024
#define TD    512
#define HH    128
#define DTILE 4
#define TTILE 64
#define ESTR  (TE + 8)              // e_s row stride: breaks d-bank aliasing
#define LOG2E 1.4426950408889634f

typedef float f32x2 __attribute__((ext_vector_type(2)));

__device__ __forceinline__ f32x2 pk_fma(f32x2 a, f32x2 b, f32x2 c) {
    return __builtin_elementwise_fma(a, b, c);
}

// Accurate-enough tanh for the proj epilogue (786K elems, off the hot path).
__device__ __forceinline__ float tanh_eval(float x) {
    float e = __builtin_amdgcn_exp2f(2.0f * LOG2E * x);
    return 1.0f - 2.0f * __builtin_amdgcn_rcpf(e + 1.0f);
}

// ---------------------------------------------------------------------------
// Kernel 1: tiled projections; epilogue applies tanh (A = tanh(enc@W),
// B = tanh(dec@U)) so the energy kernel can use the addition theorem.
// ---------------------------------------------------------------------------
__global__ __launch_bounds__(256) void proj_gemm(
    const float* __restrict__ enc, const float* __restrict__ dec,
    const float* __restrict__ Wa,  const float* __restrict__ Ua,
    float* __restrict__ out)
{
    __shared__ float Xs[64 * 33];
    __shared__ float Ws[32 * 64];

    const int tid = threadIdx.x;
    const int rt = blockIdx.x >> 1, ch = blockIdx.x & 1;
    const int r0 = rt * 64, c0 = ch * 64;

    const float* X; const float* W; int rX0;
    if (r0 < BB * TE) { X = enc; W = Wa; rX0 = r0; }
    else              { X = dec; W = Ua; rX0 = r0 - BB * TE; }

    const int c4 = tid & 15;
    const int rg = tid >> 4;

    float4 a0 = {0,0,0,0}, a1 = a0, a2 = a0, a3 = a0;

    for (int kc = 0; kc < 4; ++kc) {
        #pragma unroll
        for (int i = 0; i < 2; ++i) {
            int idx = tid + i * 256;
            int r  = idx >> 3, k4 = idx & 7;
            *(float4*)&Xs[r * 33 + k4 * 4] =
                *(const float4*)&X[(rX0 + r) * HH + kc * 32 + k4 * 4];
            int kk = idx >> 4, cc = idx & 15;
            *(float4*)&Ws[kk * 64 + cc * 4] =
                *(const float4*)&W[(kc * 32 + kk) * HH + c0 + cc * 4];
        }
        __syncthreads();
        #pragma unroll 8
        for (int k = 0; k < 32; ++k) {
            float4 wv = *(const float4*)&Ws[k * 64 + c4 * 4];
            float x0 = Xs[(rg * 4 + 0) * 33 + k];
            float x1 = Xs[(rg * 4 + 1) * 33 + k];
            float x2 = Xs[(rg * 4 + 2) * 33 + k];
            float x3 = Xs[(rg * 4 + 3) * 33 + k];
            a0.x = fmaf(x0, wv.x, a0.x); a0.y = fmaf(x0, wv.y, a0.y);
            a0.z = fmaf(x0, wv.z, a0.z); a0.w = fmaf(x0, wv.w, a0.w);
            a1.x = fmaf(x1, wv.x, a1.x); a1.y = fmaf(x1, wv.y, a1.y);
            a1.z = fmaf(x1, wv.z, a1.z); a1.w = fmaf(x1, wv.w, a1.w);
            a2.x = fmaf(x2, wv.x, a2.x); a2.y = fmaf(x2, wv.y, a2.y);
            a2.z = fmaf(x2, wv.z, a2.z); a2.w = fmaf(x2, wv.w, a2.w);
            a3.x = fmaf(x3, wv.x, a3.x); a3.y = fmaf(x3, wv.y, a3.y);
            a3.z = fmaf(x3, wv.z, a3.z); a3.w = fmaf(x3, wv.w, a3.w);
        }
        __syncthreads();
    }

    float4 accs[4] = {a0, a1, a2, a3};
    #pragma unroll
    for (int j = 0; j < 4; ++j) {
        float4 o = accs[j];
        o.x = tanh_eval(o.x); o.y = tanh_eval(o.y);
        o.z = tanh_eval(o.z); o.w = tanh_eval(o.w);
        *(float4*)&out[(r0 + rg * 4 + j) * HH + c0 + c4 * 4] = o;
    }
}

// ---------------------------------------------------------------------------
// Kernel 2: fused energies -> softmax -> context. R12 structure (depth-2,
// ESTR pad) with PACKED-F32 math: phase-1 fraction tree and phase-3 FMAs
// rewritten on f32x2 so the backend emits v_pk_fma_f32 (2 elems/slot).
// ---------------------------------------------------------------------------
__global__ __launch_bounds__(512, 4) void attn_fused(
    const float* __restrict__ enc,    // [B, TE, H] raw
    const float* __restrict__ ta,     // [B*TE, H]  = tanh(W_s)
    const float* __restrict__ tb,     // [B*TD, H]  = tanh(U_h)
    const float* __restrict__ Va,     // [H]
    float* __restrict__ c_out,        // [B, TD, H]
    float* __restrict__ e_out)        // [B, TD, TE]
{
    __shared__ float e_s[DTILE * ESTR];     // 16.1 KB
    __shared__ float c_red[8 * DTILE * HH]; // 16 KB

    const int tid = threadIdx.x;
    const int l   = tid & 63;
    const int w   = tid >> 6;            // 0..7 (row-octet owner)
    const int b   = blockIdx.x >> 7;
    const int d0  = (blockIdx.x & 127) * DTILE;

    // ---------------- Phase 1: energies ----------------
    {
        const int g  = l >> 3;           // group 0..7
        const int hl = l & 7;            // h-chunk offset within group
        const int dl = g & 3;            // this group's decoder step
        const int rh = g >> 2;           // row parity

        // Lane constants as f32x2: B, Bp = v*B, v (24 f32x2 = 48 regs).
        f32x2 Bl[4], Bh[4], Pl[4], Ph[4], Vl[4], Vh[4];
        #pragma unroll
        for (int j = 0; j < 4; ++j) {
            float4 vv = *(const float4*)&Va[(j * 8 + hl) * 4];
            float4 bb = *(const float4*)&tb[((size_t)b * TD + d0 + dl) * HH + (j * 8 + hl) * 4];
            Vl[j] = (f32x2){vv.x, vv.y};  Vh[j] = (f32x2){vv.z, vv.w};
            Bl[j] = (f32x2){bb.x, bb.y};  Bh[j] = (f32x2){bb.z, bb.w};
            Pl[j] = Vl[j] * Bl[j];        Ph[j] = Vh[j] * Bh[j];
        }

        const float* ta_b = ta + (size_t)b * TE * HH;

        // Wave w covers rows {(i>>2)*64 + w*8 + (i&3)*2 + rh}, i = 0..63.
        auto rowOf = [&](int i) {
            return ((i >> 2) << 6) + w * 8 + ((i & 3) << 1) + rh;
        };

        float4 A0[4], A1[4];
        auto loadA = [&](int i, float4 (&A)[4]) {
            const float* base = ta_b + (size_t)rowOf(i) * HH;
            #pragma unroll
            for (int j = 0; j < 4; ++j)
                A[j] = *(const float4*)&base[(j * 8 + hl) * 4];
        };

        auto p1c = [&](int i, float4 (&A)[4]) {
            const f32x2 one2 = {1.0f, 1.0f};
            f32x2 n2[8], d2[8];
            #pragma unroll
            for (int j = 0; j < 4; ++j) {
                f32x2 Al = (f32x2){A[j].x, A[j].y};
                f32x2 Ah = (f32x2){A[j].z, A[j].w};
                n2[2 * j]     = pk_fma(Vl[j], Al, Pl[j]);
                n2[2 * j + 1] = pk_fma(Vh[j], Ah, Ph[j]);
                d2[2 * j]     = pk_fma(Al, Bl[j], one2);
                d2[2 * j + 1] = pk_fma(Ah, Bh[j], one2);
            }
            // Vertical packed fraction-combine tree: 8 -> 4 -> 2 -> 1.
            #pragma unroll
            for (int s = 4; s >= 1; s >>= 1) {
                #pragma unroll
                for (int k = 0; k < s; ++k) {
                    n2[k] = pk_fma(n2[2 * k], d2[2 * k + 1], n2[2 * k + 1] * d2[2 * k]);
                    d2[k] = d2[2 * k] * d2[2 * k + 1];
                }
            }
            // Horizontal: combine the two sub-fractions in .x/.y.
            float num = n2[0].x * d2[0].y + n2[0].y * d2[0].x;
            float den = d2[0].x * d2[0].y;
            float e = num * __builtin_amdgcn_rcpf(den);
            e += __shfl_xor(e, 1);
            e += __shfl_xor(e, 2);
            e += __shfl_xor(e, 4);
            if (hl == 0) e_s[dl * ESTR + rowOf(i)] = e;
        };

        loadA(0, A0);
        #pragma unroll 1
        for (int i = 0; i < 62; i += 2) {
            loadA(i + 1, A1);
            p1c(i, A0);
            loadA(i + 2, A0);
            p1c(i + 1, A1);
        }
        loadA(63, A1);
        p1c(62, A0);
        p1c(63, A1);
    }
    __syncthreads();   // all waves' raw energies visible

    // ---------------- Phase 2: softmax (d = w&3, two waves split halves) ----
    {
        const int d2 = w & 3, hf = w >> 2;
        float ev[16];
        float m = -3.0e38f;
        #pragma unroll
        for (int i = 0; i < 16; ++i) {
            ev[i] = e_s[d2 * ESTR + i * 64 + l];
            m = fmaxf(m, ev[i]);
        }
        #pragma unroll
        for (int off = 32; off; off >>= 1) m = fmaxf(m, __shfl_xor(m, off));
        float s = 0.f;
        #pragma unroll
        for (int i = 0; i < 16; ++i) {
            ev[i] = __builtin_amdgcn_exp2f((ev[i] - m) * LOG2E);
            s += ev[i];
        }
        #pragma unroll
        for (int off = 32; off; off >>= 1) s += __shfl_xor(s, off);
        float inv = __builtin_amdgcn_rcpf(s);

        __syncthreads();   // all raw-energy reads done before overwrite
        float* eo = e_out + ((size_t)b * TD + d0 + d2) * TE;
        #pragma unroll
        for (int i = 0; i < 8; ++i) {
            int ii = hf * 8 + i;
            float p = ev[ii] * inv;
            e_s[d2 * ESTR + ii * 64 + l] = p;
            eo[ii * 64 + l] = p;
        }
        __syncthreads();   // normalized p visible to all waves
    }

    // ---------------- Phase 3: context (packed FMAs, register pingpong) -----
    const int h4 = l & 31, tsub = l >> 5;
    f32x2 accL[DTILE], accH[DTILE];
    #pragma unroll
    for (int d = 0; d < DTILE; ++d) {
        accL[d] = (f32x2){0.f, 0.f};
        accH[d] = (f32x2){0.f, 0.f};
    }

    {
        const float* enc_w = enc + ((size_t)b * TE + w * 8) * HH;
        float4 X0[4], X1[4];

        auto loadX = [&](int tt, float4 (&X)[4]) {
            const float* base = enc_w + (size_t)tt * TTILE * HH;
            #pragma unroll
            for (int k = 0; k < 4; ++k)
                X[k] = *(const float4*)&base[(tsub * 4 + k) * HH + h4 * 4];
        };

        auto p3c = [&](int tt, float4 (&X)[4]) {
            float4 ep[DTILE];
            #pragma unroll
            for (int d = 0; d < DTILE; ++d)
                ep[d] = *(const float4*)&e_s[d * ESTR + tt * TTILE + w * 8 + tsub * 4];
            #pragma unroll
            for (int k = 0; k < 4; ++k) {
                f32x2 xL = (f32x2){X[k].x, X[k].y};
                f32x2 xH = (f32x2){X[k].z, X[k].w};
                #pragma unroll
                for (int d = 0; d < DTILE; ++d) {
                    float p = k == 0 ? ep[d].x : k == 1 ? ep[d].y
                            : k == 2 ? ep[d].z : ep[d].w;
                    f32x2 pv = (f32x2){p, p};
                    accL[d] = pk_fma(pv, xL, accL[d]);
                    accH[d] = pk_fma(pv, xH, accH[d]);
                }
            }
        };

        loadX(0, X0);
        #pragma unroll 1
        for (int tt = 0; tt < 14; tt += 2) {
            loadX(tt + 1, X1);
            p3c(tt, X0);
            loadX(tt + 2, X0);
            p3c(tt + 1, X1);
        }
        loadX(15, X1);
        p3c(14, X0);
        p3c(15, X1);
    }

    // Combine tsub halves; park per-wave partials; tree-reduce across waves.
    float4 acc4[DTILE];
    #pragma unroll
    for (int d = 0; d < DTILE; ++d)
        acc4[d] = make_float4(accL[d].x, accL[d].y, accH[d].x, accH[d].y);
    #pragma unroll
    for (int d = 0; d < DTILE; ++d) {
        acc4[d].x += __shfl_xor(acc4[d].x, 32);
        acc4[d].y += __shfl_xor(acc4[d].y, 32);
        acc4[d].z += __shfl_xor(acc4[d].z, 32);
        acc4[d].w += __shfl_xor(acc4[d].w, 32);
    }
    if (tsub == 0) {
        #pragma unroll
        for (int d = 0; d < DTILE; ++d)
            *(float4*)&c_red[(w * DTILE + d) * HH + h4 * 4] = acc4[d];
    }
    __syncthreads();

    if (w < DTILE && l < 32) {
        float4 o = make_float4(0.f, 0.f, 0.f, 0.f);
        #pragma unroll
        for (int ww = 0; ww < 8; ++ww) {
            float4 p = *(const float4*)&c_red[(ww * DTILE + w) * HH + l * 4];
            o.x += p.x; o.y += p.y; o.z += p.z; o.w += p.w;
        }
        *(float4*)&c_out[((size_t)b * TD + d0 + w) * HH + l * 4] = o;
    }
}

// ---------------------------------------------------------------------------
extern "C" void kernel_launch(void* const* d_in, const int* in_sizes, int n_in,
                              void* d_out, int out_size, void* d_ws, size_t ws_size,
                              hipStream_t stream) {
    (void)in_sizes; (void)n_in; (void)out_size; (void)ws_size;

    const float* enc = (const float*)d_in[0];
    const float* dec = (const float*)d_in[1];
    const float* Wa  = (const float*)d_in[2];
    const float* Ua  = (const float*)d_in[3];
    const float* Va  = (const float*)d_in[4];

    float* c_out = (float*)d_out;
    float* e_out = (float*)d_out + BB * TD * HH;

    float* proj = (float*)d_ws;
    float* ta_p = proj;                  // tanh(W_s): [B*TE, H]
    float* tb_p = proj + BB * TE * HH;   // tanh(U_h): [B*TD, H]

    proj_gemm<<<192, 256, 0, stream>>>(enc, dec, Wa, Ua, proj);
    attn_fused<<<(BB * TD) / DTILE, 512, 0, stream>>>(enc, ta_p, tb_p, Va, c_out, e_out);
}